// Round 7
// baseline (255.356 us; speedup 1.0000x reference)
//
#include <hip/hip_runtime.h>

#define D_DIM 256
#define STEP (6.0f / 255.0f)
#define CAP_T 128        // records per 64-px tile (Poisson lambda~71 -> P(>128)~2e-10/tile)
#define LOG2E 1.4426950408889634f

// ---- Pass 1: normalize + tile-list fill. ONE THREAD PER POINT. ----
// probs ∝ exp(a*xt^2), a = -0.5*(STEP/conf)^2 (per-point const scale of
// log_prob cancels in L2 normalization). Squared-norm over the 256-window =
// F(dep) + F(254-dep), F(n) = sum_{j=0}^{n} exp(-s2*j^2) via Euler-Maclaurin:
// F(n) = sqrt(pi)/(2s)*erf(s*n) + (1+E)/2 - s2*n*E/6, E = exp(-s2*n^2).
// Record: {depth(bits), A2 = a*log2e, inv_nrm, pixel-in-tile(bits)}.
__global__ __launch_bounds__(256) void normfill_kernel(
    const int2* __restrict__ pts_pos, const int* __restrict__ pts_depth,
    const float* __restrict__ pts_conf, const int* __restrict__ feat_w,
    int* __restrict__ counts, float4* __restrict__ recs, int N)
{
    const int p = blockIdx.x * 256 + threadIdx.x;
    if (p >= N) return;

    const int dep = pts_depth[p];
    const float ic = 1.0f / pts_conf[p];
    const float s  = STEP * ic;
    const float s2 = s * s;                 // = -2a

    const float c0 = 0.8862269254527580f / s;   // sqrt(pi)/2 / s
    const float n1 = (float)dep;
    const float n2 = (float)(254 - dep);
    const float E1 = __expf(-s2 * n1 * n1);
    const float E2 = __expf(-s2 * n2 * n2);
    const float F1 = c0 * erff(s * n1) + 0.5f * (1.f + E1) - s2 * n1 * E1 * (1.f / 6.f);
    const float F2 = c0 * erff(s * n2) + 0.5f * (1.f + E2) - s2 * n2 * E2 * (1.f / 6.f);
    const float ss = F1 + F2;

    const int W = *feat_w;
    const int2 uv = pts_pos[p];
    const int lin = uv.y * W + uv.x;
    const int tileIdx = lin >> 6;
    const int c = lin & 63;
    const int slot = atomicAdd(&counts[tileIdx], 1);
    if (slot < CAP_T) {
        float4 rec;
        rec.x = __int_as_float(dep);
        rec.y = -0.5f * s2 * LOG2E;         // A2: exponent coeff in base-2
        rec.z = rsqrtf(ss);
        rec.w = __int_as_float(c);
        recs[(size_t)tileIdx * CAP_T + slot] = rec;
    }
}

// ---- Pass 2: per-tile LDS scatter + coalesced writeout. ----
// One block per 64-pixel tile. LDS tile 64KB, XOR-swizzled:
//   value(pixel c, depth d) at tile[c*256 + (d ^ c)]   (c<64 flips low 6 bits)
// Wave w owns depth slab [64w, 64w+64): the swizzle preserves the slab, so
// waves never touch each other's LDS -> no __syncthreads anywhere.
// Every record is processed by all 64 lanes (lane = depth-in-slab): uniform
// trip count, no divergence, records fetched once per wave (L2-broadcast).
__global__ __launch_bounds__(256) void gather_kernel(
    const int* __restrict__ counts, const float4* __restrict__ recs,
    float* __restrict__ out, int HW)
{
    __shared__ float tile[64 * 256];        // 64 KB
    const int wave = threadIdx.x >> 6;
    const int lane = threadIdx.x & 63;
    const int b = blockIdx.x;
    const int p0 = b * 64;
    const int dbase = wave * 64;

    // zero own slab: rows c, dword range [c*256 + dbase, +64)
    float4* t4 = (float4*)tile;
    {
        const int i4 = lane & 15;
        const int cr = lane >> 4;
#pragma unroll
        for (int it = 0; it < 16; ++it) {
            const int c = it * 4 + cr;
            t4[c * 64 + wave * 16 + i4] = make_float4(0.f, 0.f, 0.f, 0.f);
        }
    }

    int cnt = counts[b];
    cnt = cnt < CAP_T ? cnt : CAP_T;
    const float4* __restrict__ rec = recs + (size_t)b * CAP_T;

#define PROC(r)                                                         \
    {                                                                   \
        const int dep = __float_as_int((r).x);                          \
        const int c   = __float_as_int((r).w);                          \
        const int t   = dbase + lane - dep;                             \
        const float xt = (float)(t - (t > 0));                          \
        const float e  = exp2f((r).y * xt * xt) * (r).z;                \
        tile[c * 256 + dbase + (lane ^ c)] += e;                        \
    }

    int j = 0;
    for (; j + 4 <= cnt; j += 4) {          // 4 loads in flight
        const float4 r0 = rec[j];
        const float4 r1 = rec[j + 1];
        const float4 r2 = rec[j + 2];
        const float4 r3 = rec[j + 3];
        PROC(r0) PROC(r1) PROC(r2) PROC(r3)
    }
    for (; j < cnt; ++j) {
        const float4 r0 = rec[j];
        PROC(r0)
    }
#undef PROC

    // writeout own slab: row d = dbase+rr, pixel = lane -> 256 B segments
    const int pix = p0 + lane;
    if (pix < HW) {
#pragma unroll
        for (int rr = 0; rr < 64; ++rr) {
            const int d = dbase + rr;
            const float v = tile[lane * 256 + dbase + (rr ^ lane)];
            __builtin_nontemporal_store(v, out + (size_t)d * HW + pix);
        }
    }
}

// ---------------- Fallback: direct scattered atomics ----------------
__global__ __launch_bounds__(256) void scatter_direct_kernel(
    const int* __restrict__ pts_pos, const int* __restrict__ pts_depth,
    const float* __restrict__ pts_conf, const int* __restrict__ feat_w,
    float* __restrict__ out, int HW, int N)
{
    const int wave = threadIdx.x >> 6;
    const int lane = threadIdx.x & 63;
    const int p = blockIdx.x * 4 + wave;
    if (p >= N) return;

    const int W = *feat_w;
    const int lin = pts_pos[2 * p + 1] * W + pts_pos[2 * p];
    const int dep = pts_depth[p];
    const float ic = 1.0f / pts_conf[p];

    float pr[4];
    float ss = 0.f;
#pragma unroll
    for (int k = 0; k < 4; ++k) {
        const int d = lane + 64 * k;
        const int t = d - dep;
        const float x = (float)(t > 0 ? t - 1 : t) * STEP;
        const float z = x * ic;
        const float e = __expf(-0.5f * z * z);
        pr[k] = e;
        ss += e * e;
    }
#pragma unroll
    for (int off = 32; off; off >>= 1) ss += __shfl_xor(ss, off, 64);
    const float inv = rsqrtf(ss);
#pragma unroll
    for (int k = 0; k < 4; ++k) {
        const int d = lane + 64 * k;
        atomicAdd(out + (size_t)d * HW + lin, pr[k] * inv);
    }
}

extern "C" void kernel_launch(void* const* d_in, const int* in_sizes, int n_in,
                              void* d_out, int out_size, void* d_ws, size_t ws_size,
                              hipStream_t stream) {
    const int*   pts_pos   = (const int*)d_in[0];
    const int*   pts_depth = (const int*)d_in[1];
    const float* pts_conf  = (const float*)d_in[2];
    const int*   feat_w    = (const int*)d_in[4];

    const int N  = in_sizes[0] / 2;
    const int HW = out_size / D_DIM;
    float* out = (float*)d_out;

    const int tiles = (HW + 63) / 64;
    // ws layout: [recs: tiles*CAP_T float4 | counts: tiles int]
    float4* recs = (float4*)d_ws;
    int* counts  = (int*)(recs + (size_t)tiles * CAP_T);
    const size_t ws_need = (size_t)tiles * CAP_T * sizeof(float4) + (size_t)tiles * sizeof(int);

    if (ws_size >= ws_need) {
        (void)hipMemsetAsync(counts, 0, (size_t)tiles * sizeof(int), stream);
        normfill_kernel<<<(N + 255) / 256, 256, 0, stream>>>(
            (const int2*)pts_pos, pts_depth, pts_conf, feat_w, counts, recs, N);
        gather_kernel<<<tiles, 256, 0, stream>>>(counts, recs, out, HW);
    } else {
        (void)hipMemsetAsync(d_out, 0, (size_t)out_size * sizeof(float), stream);
        scatter_direct_kernel<<<(N + 3) / 4, 256, 0, stream>>>(
            pts_pos, pts_depth, pts_conf, feat_w, out, HW, N);
    }
}